// Round 3
// baseline (744.357 us; speedup 1.0000x reference)
//
#include <hip/hip_runtime.h>
#include <hip/hip_bf16.h>

#define NNODES 100000
#define NEDGES 1600000
#define BSH 7
#define NBUCK ((NNODES + 127) >> 7)   // 782 buckets of 128 nodes
#define SPBLK 1536                    // persistent spmm blocks

typedef __attribute__((ext_vector_type(8))) short bf16x8;
typedef __attribute__((ext_vector_type(4))) short bf16x4;
typedef __attribute__((ext_vector_type(2))) short bf16x2;
typedef __attribute__((ext_vector_type(4))) float f32x4;
typedef __attribute__((ext_vector_type(2))) float f32x2;

static __device__ __forceinline__ short f2bf(float f) {
  __hip_bfloat16 b = __float2bfloat16(f);
  return __builtin_bit_cast(short, b);
}
static __device__ __forceinline__ float bf2f(short s) {
  unsigned int u = ((unsigned int)(unsigned short)s) << 16;
  return __builtin_bit_cast(float, u);
}
// 8-elem fma into split lo/hi f32x4 accumulators
static __device__ __forceinline__ void fma8(f32x4& lo, f32x4& hi, float w, bf16x8 v) {
  lo[0] = fmaf(w, bf2f(v[0]), lo[0]);
  lo[1] = fmaf(w, bf2f(v[1]), lo[1]);
  lo[2] = fmaf(w, bf2f(v[2]), lo[2]);
  lo[3] = fmaf(w, bf2f(v[3]), lo[3]);
  hi[0] = fmaf(w, bf2f(v[4]), hi[0]);
  hi[1] = fmaf(w, bf2f(v[5]), hi[1]);
  hi[2] = fmaf(w, bf2f(v[6]), hi[2]);
  hi[3] = fmaf(w, bf2f(v[7]), hi[3]);
}

// async global->LDS, 16B per lane; LDS dest = wave-uniform base + lane*16
static __device__ __forceinline__ void gload16(const void* g, void* l) {
  __builtin_amdgcn_global_load_lds(
      (const __attribute__((address_space(1))) unsigned int*)g,
      (__attribute__((address_space(3))) unsigned int*)l, 16, 0, 0);
}

// ---------------- weight transpose+convert+chunk-swizzle ----------------
// Wt[n][k] holds bf16(W[ks][n]) where ks = k with its 16B-chunk index (within the
// 64-element K-tile) XORed by (n&7). gload_lds stages this linearly into LDS;
// the gemm fragment read applies the same XOR -> conflict-free, correct values.
__global__ void wtrans_kernel(const float* __restrict__ W, short* __restrict__ Wt,
                              int K, int Nvalid, int Npad) {
  int idx = blockIdx.x * blockDim.x + threadIdx.x;
  if (idx >= Npad * K) return;
  int n = idx / K, k = idx - n * K;
  int ks = (k & ~63) | ((((k >> 3) & 7) ^ (n & 7)) << 3) | (k & 7);
  Wt[idx] = (n < Nvalid) ? f2bf(W[(size_t)ks * Nvalid + n]) : (short)0;
}

// ---------------- CSR build: two-level counting sort ----------------
// P2: bucket histogram (LDS-aggregated)
__global__ void bcount_kernel(const int* __restrict__ ei, int* __restrict__ bcnt) {
  __shared__ int h[NBUCK];
  for (int i = threadIdx.x; i < NBUCK; i += 256) h[i] = 0;
  __syncthreads();
  int stride = gridDim.x * 256;
  for (int e = blockIdx.x * 256 + threadIdx.x; e < NEDGES; e += stride)
    atomicAdd(&h[ei[NEDGES + e] >> BSH], 1);
  __syncthreads();
  for (int i = threadIdx.x; i < NBUCK; i += 256)
    if (h[i]) atomicAdd(&bcnt[i], h[i]);
}

// P3: scan bucket counts -> bbase (exclusive, +sentinel), init bcur
__global__ void bscan_kernel(const int* __restrict__ bcnt, int* __restrict__ bbase,
                             int* __restrict__ bcur, int* __restrict__ rowptr) {
  __shared__ int lds[1024];
  int t = threadIdx.x;
  int c = (t < NBUCK) ? bcnt[t] : 0;
  lds[t] = c;
  __syncthreads();
  for (int off = 1; off < 1024; off <<= 1) {
    int v = (t >= off) ? lds[t - off] : 0;
    __syncthreads();
    lds[t] += v;
    __syncthreads();
  }
  if (t < NBUCK) {
    int ex = lds[t] - c;
    bbase[t] = ex;
    bcur[t] = ex;
  }
  if (t == NBUCK) bbase[t] = NEDGES;
  if (t == 0) rowptr[NNODES] = NEDGES;
}

// P4: chunked scatter into bucket segments; runs are per-block contiguous (L2-local writes)
#define P4CHUNK 8192
__global__ void bscatter_kernel(const int* __restrict__ ei, const float* __restrict__ ew,
                                int* __restrict__ bcur, int2* __restrict__ tmp) {
  __shared__ int cnt[NBUCK];
  __shared__ int pos[NBUCK];
  int tid = threadIdx.x;
  for (int i = tid; i < NBUCK; i += 256) cnt[i] = 0;
  __syncthreads();
  int base = blockIdx.x * P4CHUNK;
  int end = base + P4CHUNK;
  if (end > NEDGES) end = NEDGES;
  for (int e = base + tid; e < end; e += 256)
    atomicAdd(&cnt[ei[NEDGES + e] >> BSH], 1);
  __syncthreads();
  for (int i = tid; i < NBUCK; i += 256)
    if (cnt[i]) pos[i] = atomicAdd(&bcur[i], cnt[i]);
  __syncthreads();
  for (int e = base + tid; e < end; e += 256) {
    int d = ei[NEDGES + e];
    int b = d >> BSH;
    int p = atomicAdd(&pos[b], 1);
    tmp[p] = make_int2(ei[e] | ((d & 127) << 17), __float_as_int(ew[e]));  // src<2^17
  }
}

// P5: one block per bucket — exact per-node sort within the 128-node window,
// writes rowptr + final edat (all writes in a single-owner 16KB window)
__global__ void bsort_kernel(const int* __restrict__ bbase, const int2* __restrict__ tmp,
                             int2* __restrict__ edat, int* __restrict__ rowptr) {
  __shared__ int hist[128];
  __shared__ int cur[128];
  int b = blockIdx.x;
  int tid = threadIdx.x;
  int base = bbase[b], cnt = bbase[b + 1] - base;
  if (tid < 128) hist[tid] = 0;
  __syncthreads();
  for (int i = tid; i < cnt; i += 256)
    atomicAdd(&hist[(tmp[base + i].x >> 17) & 127], 1);
  __syncthreads();
  int c = (tid < 128) ? hist[tid] : 0;
  if (tid < 128) cur[tid] = c;
  __syncthreads();
  for (int off = 1; off < 128; off <<= 1) {
    int v = (tid < 128 && tid >= off) ? cur[tid - off] : 0;
    __syncthreads();
    if (tid < 128) cur[tid] += v;
    __syncthreads();
  }
  if (tid < 128) {
    int ex = cur[tid] - c;
    int node = (b << BSH) + tid;
    if (node < NNODES) rowptr[node] = base + ex;
    cur[tid] = base + ex;
  }
  __syncthreads();
  for (int i = tid; i < cnt; i += 256) {
    int2 r = tmp[base + i];
    int d = (r.x >> 17) & 127;
    int p = atomicAdd(&cur[d], 1);
    edat[p] = make_int2(r.x & 0x1FFFF, r.y);
  }
}

// ---------------- tiled MFMA GEMM: 128x128 tile, BK=64, 4 waves of 64x64 ----------------
// B (and A when bf16) staged via global_load_lds into LINEAR [128][64] LDS; the source
// arrays are chunk-pre-swizzled (wtrans / spmm epilogues), fragment reads XOR the chunk
// index with (row&7) -> bank-conflict-free without padding, no VGPR round-trip.
// A fp32 path (gemm1) keeps reg-staged+converted padded LDS.
#define LDSTR 72
template <bool AF32, int EPI>
__launch_bounds__(256, 2)
__global__ void gemm_tiled(const void* __restrict__ Aptr, int K,
                           const short* __restrict__ Wt,
                           void* __restrict__ Cp0, float* __restrict__ Cp1,
                           const float* __restrict__ bias, int nvalid, int ldc) {
  __shared__ __align__(16) short As[128 * (AF32 ? LDSTR : 64)];
  __shared__ __align__(16) short Bs[128 * 64];
  int tid = threadIdx.x;
  int lane = tid & 63, wv = tid >> 6;
  int wr = wv >> 1, wc = wv & 1;
  int m0 = blockIdx.y * 128;
  int n0 = blockIdx.x * 128;
  f32x4 acc[4][4];
#pragma unroll
  for (int i = 0; i < 4; i++)
#pragma unroll
    for (int j = 0; j < 4; j++) acc[i][j] = (f32x4){0.f, 0.f, 0.f, 0.f};

  int srow = tid >> 3;
  int scol = (tid & 7) * 8;

  for (int k0 = 0; k0 < K; k0 += 64) {
    if constexpr (AF32) {
#pragma unroll
      for (int p = 0; p < 4; p++) {
        int ml = p * 32 + srow;
        int arow = m0 + ml;
        if (arow >= NNODES) arow = NNODES - 1;
        const float* ap = (const float*)Aptr + (size_t)arow * K + k0 + scol;
        f32x4 a0 = *(const f32x4*)ap;
        f32x4 a1 = *(const f32x4*)(ap + 4);
        bf16x8 av;
#pragma unroll
        for (int j = 0; j < 4; j++) { av[j] = f2bf(a0[j]); av[4 + j] = f2bf(a1[j]); }
        *(bf16x8*)&As[ml * LDSTR + scol] = av;
      }
    } else {
#pragma unroll
      for (int p = 0; p < 4; p++) {
        int row = p * 32 + wv * 8 + (lane >> 3);
        int arow = m0 + row;
        if (arow >= NNODES) arow = NNODES - 1;
        gload16((const short*)Aptr + (size_t)arow * K + k0 + (lane & 7) * 8,
                &As[p * 2048 + wv * 512]);
      }
    }
#pragma unroll
    for (int p = 0; p < 4; p++) {
      int row = p * 32 + wv * 8 + (lane >> 3);
      gload16(Wt + (size_t)(n0 + row) * K + k0 + (lane & 7) * 8,
              &Bs[p * 2048 + wv * 512]);
    }
    __syncthreads();
    int r = lane & 15, quad = lane >> 4;
#pragma unroll
    for (int kk = 0; kk < 64; kk += 32) {
      int csw = (kk + quad * 8) ^ ((r & 7) << 3);
      bf16x8 af[4], bfr[4];
#pragma unroll
      for (int i = 0; i < 4; i++) {
        if constexpr (AF32)
          af[i] = *(const bf16x8*)&As[(wr * 64 + i * 16 + r) * LDSTR + kk + quad * 8];
        else
          af[i] = *(const bf16x8*)&As[((wr * 64 + i * 16 + r) << 6) + csw];
      }
#pragma unroll
      for (int j = 0; j < 4; j++)
        bfr[j] = *(const bf16x8*)&Bs[((wc * 64 + j * 16 + r) << 6) + csw];
#pragma unroll
      for (int i = 0; i < 4; i++)
#pragma unroll
        for (int j = 0; j < 4; j++)
          acc[i][j] = __builtin_amdgcn_mfma_f32_16x16x32_bf16(af[i], bfr[j], acc[i][j], 0, 0, 0);
    }
    __syncthreads();
  }

  int quad = lane >> 4, cl = lane & 15;
#pragma unroll
  for (int i = 0; i < 4; i++) {
    int rowb = m0 + wr * 64 + i * 16 + quad * 4;
#pragma unroll
    for (int rr = 0; rr < 4; rr++) {
      int row = rowb + rr;
      if (row < NNODES) {
#pragma unroll
        for (int j = 0; j < 4; j++) {
          int col = n0 + wc * 64 + j * 16 + cl;
          float v = acc[i][j][rr];
          if (EPI == 0) {
            ((short*)Cp0)[(size_t)row * ldc + col] = f2bf(v);
          } else if (EPI == 1) {
            if (col < nvalid) Cp1[(size_t)row * nvalid + col] = v;
          } else {
            if (col < 128) ((short*)Cp0)[(size_t)row * 128 + col] = f2bf(v);
            else Cp1[(size_t)row * 128 + (col - 128)] = v + bias[col - 128];
          }
        }
      }
    }
  }
}

// ---------------- paired-row SpMM gathers ----------------
// pgat1 (d=256): ONE wave-inst gathers TWO rows — lanes 0-31 edge b+2j, lanes 32-63
// edge b+2j+1, 16B/lane. Edge (src,w) distributed per half via ds_bpermute.
// pgat2 (d=128): ONE wave-inst gathers FOUR rows (16 lanes each).
// Padded edge slots (>= wcnt) carry (src=0,w=0): gather row 0 (hot), contribute 0.

template <int NE>
static __device__ __forceinline__ void pgat1(int2 me, int b, int idx0, const short* Sc,
                                             f32x4* acc) {
  int s[NE]; float wt[NE]; bf16x8 v[NE];
#pragma unroll
  for (int j = 0; j < NE; j++) {
    int idx = idx0 + ((b + 2 * j) << 2);
    s[j] = __builtin_amdgcn_ds_bpermute(idx, me.x);
    wt[j] = __builtin_bit_cast(float, __builtin_amdgcn_ds_bpermute(idx, me.y));
  }
#pragma unroll
  for (int j = 0; j < NE; j++) v[j] = *(const bf16x8*)(Sc + (size_t)s[j] * 256);
#pragma unroll
  for (int j = 0; j < NE; j++)
    fma8(acc[(j & 1) * 2], acc[(j & 1) * 2 + 1], wt[j], v[j]);
}

template <int NE>
static __device__ __forceinline__ void pgat2(int2 me, int b, int idx0, const short* Sc,
                                             f32x4* acc) {
  int s[NE]; float wt[NE]; bf16x8 v[NE];
#pragma unroll
  for (int j = 0; j < NE; j++) {
    int idx = idx0 + ((b + 4 * j) << 2);
    s[j] = __builtin_amdgcn_ds_bpermute(idx, me.x);
    wt[j] = __builtin_bit_cast(float, __builtin_amdgcn_ds_bpermute(idx, me.y));
  }
#pragma unroll
  for (int j = 0; j < NE; j++) v[j] = *(const bf16x8*)(Sc + (size_t)s[j] * 128);
#pragma unroll
  for (int j = 0; j < NE; j++)
    fma8(acc[(j & 1) * 2], acc[(j & 1) * 2 + 1], wt[j], v[j]);
}

template <int NE>
static __device__ __forceinline__ void gat3(int2 me, int b, const float* S3l,
                                            float& acc0, float& acc1) {
  int src[NE]; float wt[NE]; float v[NE];
#pragma unroll
  for (int j = 0; j < NE; j++) {
    src[j] = __builtin_amdgcn_readlane(me.x, b + j);
    wt[j] = __builtin_bit_cast(float, __builtin_amdgcn_readlane(me.y, b + j));
  }
#pragma unroll
  for (int j = 0; j < NE; j++) v[j] = S3l[(size_t)src[j] * 40];
#pragma unroll
  for (int j = 0; j < NE; j++) {
    if (j & 1) acc1 = fmaf(wt[j], v[j], acc1); else acc0 = fmaf(wt[j], v[j], acc0);
  }
}

// ---------------- SpMM d=256 bf16: 2 rows/gather-inst, persistent waves ----------------
// Output Hbf chunk-swizzled (per gemm gload_lds contract): 16B chunk q within each
// 64-elem K-tile stored at q ^ (node&7).
__launch_bounds__(256, 4)
__global__ void spmm1_kernel(const int* __restrict__ rowptr, const int2* __restrict__ edat,
                             const short* __restrict__ S,
                             const float* __restrict__ bias, short* __restrict__ H) {
  int nw = gridDim.x * 4;
  int wid = blockIdx.x * 4 + (threadIdx.x >> 6);
  int lane = threadIdx.x & 63;
  int half = lane >> 5, sub = lane & 31;
  int idx0 = half << 2;
  const short* Sc = S + sub * 8;
  f32x4 bv0 = *(const f32x4*)(bias + sub * 8);
  f32x4 bv1 = *(const f32x4*)(bias + sub * 8 + 4);
  for (int node = wid; node < NNODES; node += nw) {
    f32x4 acc[4];
#pragma unroll
    for (int i = 0; i < 4; i++) acc[i] = (f32x4){0.f, 0.f, 0.f, 0.f};
    int beg = rowptr[node], end = rowptr[node + 1];
    for (int w0 = beg; w0 < end; w0 += 64) {
      int wcnt = end - w0;
      if (wcnt > 64) wcnt = 64;
      int2 me = (lane < wcnt) ? edat[w0 + lane] : make_int2(0, 0);
      int left = wcnt, b = 0;
      while (left >= 16) { pgat1<8>(me, b, idx0, Sc, acc); b += 16; left -= 16; }
      if (left > 8) pgat1<8>(me, b, idx0, Sc, acc);
      else if (left > 4) pgat1<4>(me, b, idx0, Sc, acc);
      else if (left > 2) pgat1<2>(me, b, idx0, Sc, acc);
      else if (left > 0) pgat1<1>(me, b, idx0, Sc, acc);
    }
    f32x4 lo, hi;
#pragma unroll
    for (int i = 0; i < 4; i++) {
      lo[i] = acc[0][i] + acc[2][i];
      hi[i] = acc[1][i] + acc[3][i];
      lo[i] += __shfl_xor(lo[i], 32);
      hi[i] += __shfl_xor(hi[i], 32);
    }
    if (half == 0) {
      bf16x8 h;
#pragma unroll
      for (int j = 0; j < 4; j++) {
        h[j] = f2bf(fmaxf(lo[j] + bv0[j], 0.f));
        h[4 + j] = f2bf(fmaxf(hi[j] + bv1[j], 0.f));
      }
      int t = sub >> 3, q = sub & 7;
      int off = t * 64 + ((q ^ (node & 7)) << 3);
      *(bf16x8*)(H + (size_t)node * 256 + off) = h;
    }
  }
}

// ---------------- SpMM d=128 bf16: 4 rows/gather-inst, persistent waves ----------------
// Output Tbf chunk-swizzled like Hbf (consumed by gemm3's gload_lds A-staging).
__launch_bounds__(256, 4)
__global__ void spmm2_kernel(const int* __restrict__ rowptr, const int2* __restrict__ edat,
                             const short* __restrict__ S,
                             const float* __restrict__ bias, short* __restrict__ H) {
  int nw = gridDim.x * 4;
  int wid = blockIdx.x * 4 + (threadIdx.x >> 6);
  int lane = threadIdx.x & 63;
  int q4 = lane >> 4, sub = lane & 15;
  int idx0 = q4 << 2;
  const short* Sc = S + sub * 8;
  f32x4 bv0 = *(const f32x4*)(bias + sub * 8);
  f32x4 bv1 = *(const f32x4*)(bias + sub * 8 + 4);
  for (int node = wid; node < NNODES; node += nw) {
    f32x4 acc[4];
#pragma unroll
    for (int i = 0; i < 4; i++) acc[i] = (f32x4){0.f, 0.f, 0.f, 0.f};
    int beg = rowptr[node], end = rowptr[node + 1];
    for (int w0 = beg; w0 < end; w0 += 64) {
      int wcnt = end - w0;
      if (wcnt > 64) wcnt = 64;
      int2 me = (lane < wcnt) ? edat[w0 + lane] : make_int2(0, 0);
      int left = wcnt, b = 0;
      while (left >= 32) { pgat2<8>(me, b, idx0, Sc, acc); b += 32; left -= 32; }
      if (left > 16) pgat2<8>(me, b, idx0, Sc, acc);
      else if (left > 8) pgat2<4>(me, b, idx0, Sc, acc);
      else if (left > 4) pgat2<2>(me, b, idx0, Sc, acc);
      else if (left > 0) pgat2<1>(me, b, idx0, Sc, acc);
    }
    f32x4 lo, hi;
#pragma unroll
    for (int i = 0; i < 4; i++) {
      lo[i] = acc[0][i] + acc[2][i];
      hi[i] = acc[1][i] + acc[3][i];
      lo[i] += __shfl_xor(lo[i], 32);
      hi[i] += __shfl_xor(hi[i], 32);
      lo[i] += __shfl_xor(lo[i], 16);
      hi[i] += __shfl_xor(hi[i], 16);
    }
    if (q4 == 0) {
      bf16x8 h;
#pragma unroll
      for (int j = 0; j < 4; j++) {
        h[j] = f2bf(fmaxf(lo[j] + bv0[j], 0.f));
        h[4 + j] = f2bf(fmaxf(hi[j] + bv1[j], 0.f));
      }
      int t = sub >> 3, q = sub & 7;
      int off = t * 64 + ((q ^ (node & 7)) << 3);
      *(bf16x8*)(H + (size_t)node * 128 + off) = h;
    }
  }
}

// ---------------- SpMM d=40 f32 + bias + log_softmax: persistent waves, 16 in flight ----------------
// Lanes 40..63 gather garbage (S3 padded by 64 floats; src*40+lane stays in-bounds) and are
// excluded from the softmax reduce via -inf / 0 masking.
__launch_bounds__(256, 6)
__global__ void spmm3_kernel(const int* __restrict__ rowptr, const int2* __restrict__ edat,
                             const float* __restrict__ S3,
                             const float* __restrict__ b3, float* __restrict__ out1) {
  int nw = gridDim.x * 4;
  int wid = blockIdx.x * 4 + (threadIdx.x >> 6);
  int lane = threadIdx.x & 63;
  bool act = lane < 40;
  const float* S3l = S3 + lane;
  float bl = act ? b3[lane] : 0.f;
  for (int node = wid; node < NNODES; node += nw) {
    float acc0 = 0.f, acc1 = 0.f;
    int beg = rowptr[node], end = rowptr[node + 1];
    for (int w0 = beg; w0 < end; w0 += 64) {
      int wcnt = end - w0;
      if (wcnt > 64) wcnt = 64;
      int2 me = (lane < wcnt) ? edat[w0 + lane] : make_int2(0, 0);
      int g16 = wcnt >> 4, rem = wcnt & 15;
      int b = 0;
      for (int g = 0; g < g16; ++g, b += 16) gat3<16>(me, b, S3l, acc0, acc1);
      if (rem) {
        if (rem > 8) gat3<16>(me, b, S3l, acc0, acc1);
        else gat3<8>(me, b, S3l, acc0, acc1);
      }
    }
    float acc = acc0 + acc1 + bl;
    float v = act ? acc : -__builtin_inff();
    for (int off = 32; off > 0; off >>= 1) v = fmaxf(v, __shfl_xor(v, off));
    float e = act ? expf(acc - v) : 0.f;
    for (int off = 32; off > 0; off >>= 1) e += __shfl_xor(e, off);
    float ls = logf(e);
    if (act) out1[(size_t)node * 40 + lane] = acc - v - ls;
  }
}

extern "C" void kernel_launch(void* const* d_in, const int* in_sizes, int n_in,
                              void* d_out, int out_size, void* d_ws, size_t ws_size,
                              hipStream_t stream) {
  const float* x  = (const float*)d_in[0];
  const int*   ei = (const int*)d_in[1];
  const float* ew = (const float*)d_in[2];
  const float* W1 = (const float*)d_in[3];
  const float* b1 = (const float*)d_in[4];
  const float* W2 = (const float*)d_in[5];
  const float* b2 = (const float*)d_in[6];
  const float* W3 = (const float*)d_in[7];
  const float* b3 = (const float*)d_in[8];
  const float* We = (const float*)d_in[9];
  const float* be = (const float*)d_in[10];
  float* out1 = (float*)d_out;
  float* out2 = (float*)d_out + (size_t)NNODES * 40;

  char* w = (char*)d_ws;
  size_t off = 0;
  auto alloc = [&](size_t bytes) -> char* {
    char* p = w + off;
    off += (bytes + 255) & ~(size_t)255;
    return p;
  };
  int*   rowptr = (int*)alloc((size_t)(NNODES + 1) * 4);
  int*   bcnt   = (int*)alloc((size_t)NBUCK * 4);
  int*   bbase  = (int*)alloc((size_t)(NBUCK + 1) * 4);
  int*   bcur   = (int*)alloc((size_t)NBUCK * 4);
  int2*  edat   = (int2*)alloc((size_t)NEDGES * 8);
  short* Wt1    = (short*)alloc((size_t)256 * 512 * 2);
  short* Wt2e   = (short*)alloc((size_t)256 * 256 * 2);
  short* Wt3    = (short*)alloc((size_t)128 * 128 * 2);
  short* S1bf   = (short*)alloc((size_t)NNODES * 256 * 2);
  short* Hbf    = (short*)alloc((size_t)NNODES * 256 * 2);
  short* S2bf   = (short*)alloc((size_t)NNODES * 128 * 2);
  short* Tbf    = (short*)alloc((size_t)NNODES * 128 * 2);
  float* S3     = (float*)alloc(((size_t)NNODES * 40 + 64) * 4);  // +64 floats: lane 40..63 overread pad
  int2*  tmp    = (int2*)S3;  // alias: tmp (12.8 MB) dead before gemm3 writes S3

  // --- CSR build: two-level counting sort ---
  hipMemsetAsync(bcnt, 0, (size_t)NBUCK * 4, stream);
  bcount_kernel<<<256, 256, 0, stream>>>(ei, bcnt);
  bscan_kernel<<<1, 1024, 0, stream>>>(bcnt, bbase, bcur, rowptr);
  bscatter_kernel<<<(NEDGES + P4CHUNK - 1) / P4CHUNK, 256, 0, stream>>>(ei, ew, bcur, tmp);
  bsort_kernel<<<NBUCK, 256, 0, stream>>>(bbase, tmp, edat, rowptr);

  // --- weight transpose+bf16 (chunk-swizzled for gload_lds staging) ---
  wtrans_kernel<<<(256 * 512 + 255) / 256, 256, 0, stream>>>(W1, Wt1, 512, 256, 256);
  wtrans_kernel<<<(128 * 256 + 255) / 256, 256, 0, stream>>>(W2, Wt2e, 256, 128, 128);
  wtrans_kernel<<<(128 * 256 + 255) / 256, 256, 0, stream>>>(We, Wt2e + (size_t)128 * 256, 256, 128, 128);
  wtrans_kernel<<<(128 * 128 + 255) / 256, 256, 0, stream>>>(W3, Wt3, 128, 40, 128);

  int gblocks = (NNODES + 127) / 128;

  gemm_tiled<true, 0><<<dim3(2, gblocks), 256, 0, stream>>>(x, 512, Wt1, S1bf, nullptr, nullptr, 256, 256);
  spmm1_kernel<<<SPBLK, 256, 0, stream>>>(rowptr, edat, S1bf, b1, Hbf);
  gemm_tiled<false, 2><<<dim3(2, gblocks), 256, 0, stream>>>(Hbf, 256, Wt2e, S2bf, out2, be, 256, 128);
  spmm2_kernel<<<SPBLK, 256, 0, stream>>>(rowptr, edat, S2bf, b2, Tbf);
  gemm_tiled<false, 1><<<dim3(1, gblocks), 256, 0, stream>>>(Tbf, 128, Wt3, nullptr, S3, nullptr, 40, 40);
  spmm3_kernel<<<SPBLK, 256, 0, stream>>>(rowptr, edat, S3, b3, out1);
}

// Round 4
// 712.284 us; speedup vs baseline: 1.0450x; 1.0450x over previous
//
#include <hip/hip_runtime.h>
#include <hip/hip_bf16.h>

#define NNODES 100000
#define NEDGES 1600000
#define BSH 7
#define NBUCK ((NNODES + 127) >> 7)   // 782 buckets of 128 nodes
#define SPBLK 1536                    // persistent spmm blocks
#define P4CHUNK 8192
#define NSCAT ((NEDGES + P4CHUNK - 1) / P4CHUNK)  // 196 bscatter blocks
#define MH1 391                       // gemm1 m-tiles fused with bscatter (rest with bsort)

typedef __attribute__((ext_vector_type(8))) short bf16x8;
typedef __attribute__((ext_vector_type(4))) short bf16x4;
typedef __attribute__((ext_vector_type(2))) short bf16x2;
typedef __attribute__((ext_vector_type(4))) float f32x4;
typedef __attribute__((ext_vector_type(2))) float f32x2;

static __device__ __forceinline__ short f2bf(float f) {
  __hip_bfloat16 b = __float2bfloat16(f);
  return __builtin_bit_cast(short, b);
}
static __device__ __forceinline__ float bf2f(short s) {
  unsigned int u = ((unsigned int)(unsigned short)s) << 16;
  return __builtin_bit_cast(float, u);
}
static __device__ __forceinline__ void fma4(f32x4& a, float w, bf16x4 v) {
  a[0] = fmaf(w, bf2f(v[0]), a[0]);
  a[1] = fmaf(w, bf2f(v[1]), a[1]);
  a[2] = fmaf(w, bf2f(v[2]), a[2]);
  a[3] = fmaf(w, bf2f(v[3]), a[3]);
}
static __device__ __forceinline__ void fma2(f32x2& a, float w, bf16x2 v) {
  a[0] = fmaf(w, bf2f(v[0]), a[0]);
  a[1] = fmaf(w, bf2f(v[1]), a[1]);
}

// async global->LDS, 16B per lane; LDS dest = wave-uniform base + lane*16
static __device__ __forceinline__ void gload16(const void* g, void* l) {
  __builtin_amdgcn_global_load_lds(
      (const __attribute__((address_space(1))) unsigned int*)g,
      (__attribute__((address_space(3))) unsigned int*)l, 16, 0, 0);
}

// ---------------- weight transpose+convert+chunk-swizzle (body) ----------------
// Wt[n][k] holds bf16(W[ks][n]) where ks = k with its 16B-chunk index (within the
// 64-element K-tile) XORed by (n&7). gload_lds stages this linearly into LDS;
// the gemm fragment read applies the same XOR -> conflict-free, correct values.
static __device__ __forceinline__ void wtrans_body(int blk, const float* __restrict__ W,
                                                   short* __restrict__ Wt,
                                                   int K, int Nvalid, int Npad) {
  int idx = blk * 256 + threadIdx.x;
  if (idx >= Npad * K) return;
  int n = idx / K, k = idx - n * K;
  int ks = (k & ~63) | ((((k >> 3) & 7) ^ (n & 7)) << 3) | (k & 7);
  Wt[idx] = (n < Nvalid) ? f2bf(W[(size_t)ks * Nvalid + n]) : (short)0;
}

// ---------------- CSR build bodies ----------------
static __device__ __forceinline__ void bcount_body(int blk, const int* __restrict__ ei,
                                                   int* __restrict__ bcnt, int* h) {
  for (int i = threadIdx.x; i < NBUCK; i += 256) h[i] = 0;
  __syncthreads();
  for (int e = blk * 256 + threadIdx.x; e < NEDGES; e += 256 * 256)
    atomicAdd(&h[ei[NEDGES + e] >> BSH], 1);
  __syncthreads();
  for (int i = threadIdx.x; i < NBUCK; i += 256)
    if (h[i]) atomicAdd(&bcnt[i], h[i]);
}

static __device__ __forceinline__ void bscatter_body(int blk, int* cnt, int* pos,
                                                     const int* __restrict__ ei,
                                                     const float* __restrict__ ew,
                                                     int* __restrict__ bcur,
                                                     int2* __restrict__ tmp) {
  int tid = threadIdx.x;
  for (int i = tid; i < NBUCK; i += 256) cnt[i] = 0;
  __syncthreads();
  int base = blk * P4CHUNK;
  int end = base + P4CHUNK;
  if (end > NEDGES) end = NEDGES;
  for (int e = base + tid; e < end; e += 256)
    atomicAdd(&cnt[ei[NEDGES + e] >> BSH], 1);
  __syncthreads();
  for (int i = tid; i < NBUCK; i += 256)
    if (cnt[i]) pos[i] = atomicAdd(&bcur[i], cnt[i]);
  __syncthreads();
  for (int e = base + tid; e < end; e += 256) {
    int d = ei[NEDGES + e];
    int b = d >> BSH;
    int p = atomicAdd(&pos[b], 1);
    tmp[p] = make_int2(ei[e] | ((d & 127) << 17), __float_as_int(ew[e]));  // src<2^17
  }
}

static __device__ __forceinline__ void bsort_body(int b, int* hist, int* cur,
                                                  const int* __restrict__ bbase,
                                                  const int2* __restrict__ tmp,
                                                  int2* __restrict__ edat,
                                                  int* __restrict__ rowptr) {
  int tid = threadIdx.x;
  int base = bbase[b], cnt = bbase[b + 1] - base;
  if (tid < 128) hist[tid] = 0;
  __syncthreads();
  for (int i = tid; i < cnt; i += 256)
    atomicAdd(&hist[(tmp[base + i].x >> 17) & 127], 1);
  __syncthreads();
  int c = (tid < 128) ? hist[tid] : 0;
  if (tid < 128) cur[tid] = c;
  __syncthreads();
  for (int off = 1; off < 128; off <<= 1) {
    int v = (tid < 128 && tid >= off) ? cur[tid - off] : 0;
    __syncthreads();
    if (tid < 128) cur[tid] += v;
    __syncthreads();
  }
  if (tid < 128) {
    int ex = cur[tid] - c;
    int node = (b << BSH) + tid;
    if (node < NNODES) rowptr[node] = base + ex;
    cur[tid] = base + ex;
  }
  __syncthreads();
  for (int i = tid; i < cnt; i += 256) {
    int2 r = tmp[base + i];
    int d = (r.x >> 17) & 127;
    int p = atomicAdd(&cur[d], 1);
    edat[p] = make_int2(r.x & 0x1FFFF, r.y);
  }
}

// P3: scan bucket counts -> bbase (exclusive, +sentinel), init bcur (standalone, 1 block)
__global__ void bscan_kernel(const int* __restrict__ bcnt, int* __restrict__ bbase,
                             int* __restrict__ bcur, int* __restrict__ rowptr) {
  __shared__ int lds[1024];
  int t = threadIdx.x;
  int c = (t < NBUCK) ? bcnt[t] : 0;
  lds[t] = c;
  __syncthreads();
  for (int off = 1; off < 1024; off <<= 1) {
    int v = (t >= off) ? lds[t - off] : 0;
    __syncthreads();
    lds[t] += v;
    __syncthreads();
  }
  if (t < NBUCK) {
    int ex = lds[t] - c;
    bbase[t] = ex;
    bcur[t] = ex;
  }
  if (t == NBUCK) bbase[t] = NEDGES;
  if (t == 0) rowptr[NNODES] = NEDGES;
}

// ---------------- tiled MFMA GEMM body: 128x128 tile, BK=64, 4 waves of 64x64 ----------------
// B (and A when bf16) staged via global_load_lds into LINEAR [128][64] LDS; sources are
// chunk-pre-swizzled (wtrans / spmm epilogues), fragment reads XOR the chunk index with
// (row&7). A fp32 path keeps reg-staged+converted padded LDS.
#define LDSTR 72
template <bool AF32, int EPI>
static __device__ void gemm_body(int my, int nx, short* As, short* Bs,
                                 const void* __restrict__ Aptr, int K,
                                 const short* __restrict__ Wt,
                                 void* __restrict__ Cp0, float* __restrict__ Cp1,
                                 const float* __restrict__ bias, int nvalid, int ldc) {
  int tid = threadIdx.x;
  int lane = tid & 63, wv = tid >> 6;
  int wr = wv >> 1, wc = wv & 1;
  int m0 = my * 128;
  int n0 = nx * 128;
  f32x4 acc[4][4];
#pragma unroll
  for (int i = 0; i < 4; i++)
#pragma unroll
    for (int j = 0; j < 4; j++) acc[i][j] = (f32x4){0.f, 0.f, 0.f, 0.f};

  int srow = tid >> 3;
  int scol = (tid & 7) * 8;

  for (int k0 = 0; k0 < K; k0 += 64) {
    if constexpr (AF32) {
#pragma unroll
      for (int p = 0; p < 4; p++) {
        int ml = p * 32 + srow;
        int arow = m0 + ml;
        if (arow >= NNODES) arow = NNODES - 1;
        const float* ap = (const float*)Aptr + (size_t)arow * K + k0 + scol;
        f32x4 a0 = *(const f32x4*)ap;
        f32x4 a1 = *(const f32x4*)(ap + 4);
        bf16x8 av;
#pragma unroll
        for (int j = 0; j < 4; j++) { av[j] = f2bf(a0[j]); av[4 + j] = f2bf(a1[j]); }
        *(bf16x8*)&As[ml * LDSTR + scol] = av;
      }
    } else {
#pragma unroll
      for (int p = 0; p < 4; p++) {
        int row = p * 32 + wv * 8 + (lane >> 3);
        int arow = m0 + row;
        if (arow >= NNODES) arow = NNODES - 1;
        gload16((const short*)Aptr + (size_t)arow * K + k0 + (lane & 7) * 8,
                &As[p * 2048 + wv * 512]);
      }
    }
#pragma unroll
    for (int p = 0; p < 4; p++) {
      int row = p * 32 + wv * 8 + (lane >> 3);
      gload16(Wt + (size_t)(n0 + row) * K + k0 + (lane & 7) * 8,
              &Bs[p * 2048 + wv * 512]);
    }
    __syncthreads();
    int r = lane & 15, quad = lane >> 4;
#pragma unroll
    for (int kk = 0; kk < 64; kk += 32) {
      int csw = (kk + quad * 8) ^ ((r & 7) << 3);
      bf16x8 af[4], bfr[4];
#pragma unroll
      for (int i = 0; i < 4; i++) {
        if constexpr (AF32)
          af[i] = *(const bf16x8*)&As[(wr * 64 + i * 16 + r) * LDSTR + kk + quad * 8];
        else
          af[i] = *(const bf16x8*)&As[((wr * 64 + i * 16 + r) << 6) + csw];
      }
#pragma unroll
      for (int j = 0; j < 4; j++)
        bfr[j] = *(const bf16x8*)&Bs[((wc * 64 + j * 16 + r) << 6) + csw];
#pragma unroll
      for (int i = 0; i < 4; i++)
#pragma unroll
        for (int j = 0; j < 4; j++)
          acc[i][j] = __builtin_amdgcn_mfma_f32_16x16x32_bf16(af[i], bfr[j], acc[i][j], 0, 0, 0);
    }
    __syncthreads();
  }

  int quad = lane >> 4, cl = lane & 15;
#pragma unroll
  for (int i = 0; i < 4; i++) {
    int rowb = m0 + wr * 64 + i * 16 + quad * 4;
#pragma unroll
    for (int rr = 0; rr < 4; rr++) {
      int row = rowb + rr;
      if (row < NNODES) {
#pragma unroll
        for (int j = 0; j < 4; j++) {
          int col = n0 + wc * 64 + j * 16 + cl;
          float v = acc[i][j][rr];
          if (EPI == 0) {
            ((short*)Cp0)[(size_t)row * ldc + col] = f2bf(v);
          } else if (EPI == 1) {
            if (col < nvalid) Cp1[(size_t)row * nvalid + col] = v;
          } else {
            if (col < 128) ((short*)Cp0)[(size_t)row * 128 + col] = f2bf(v);
            else Cp1[(size_t)row * 128 + (col - 128)] = v + bias[col - 128];
          }
        }
      }
    }
  }
}

// standalone gemm kernel (gemm2, gemm3)
template <bool AF32, int EPI>
__launch_bounds__(256, 2)
__global__ void gemm_tiled(const void* __restrict__ Aptr, int K,
                           const short* __restrict__ Wt,
                           void* __restrict__ Cp0, float* __restrict__ Cp1,
                           const float* __restrict__ bias, int nvalid, int ldc) {
  __shared__ __align__(16) short As[128 * (AF32 ? LDSTR : 64)];
  __shared__ __align__(16) short Bs[128 * 64];
  gemm_body<AF32, EPI>(blockIdx.y, blockIdx.x, As, Bs, Aptr, K, Wt, Cp0, Cp1, bias, nvalid, ldc);
}

// ---------------- fused front: wtrans x4 + bcount (all independent) ----------------
__launch_bounds__(256)
__global__ void front_kernel(const float* __restrict__ W1, short* __restrict__ Wt1,
                             const float* __restrict__ W2, const float* __restrict__ We,
                             short* __restrict__ Wt2e, const float* __restrict__ W3,
                             short* __restrict__ Wt3,
                             const int* __restrict__ ei, int* __restrict__ bcnt) {
  __shared__ int h[NBUCK];
  int b = blockIdx.x;
  if (b < 256) { bcount_body(b, ei, bcnt, h); return; }
  b -= 256;
  if (b < 512) { wtrans_body(b, W1, Wt1, 512, 256, 256); return; }
  b -= 512;
  if (b < 128) { wtrans_body(b, W2, Wt2e, 256, 128, 128); return; }
  b -= 128;
  if (b < 128) { wtrans_body(b, We, Wt2e + (size_t)128 * 256, 256, 128, 128); return; }
  b -= 128;
  wtrans_body(b, W3, Wt3, 128, 40, 128);
}
#define FRONT_BLOCKS (256 + 512 + 128 + 128 + 64)

// ---------------- fuseA: bscatter (first) || gemm1 m-tiles [0, MH1) ----------------
__launch_bounds__(256, 2)
__global__ void fuseA_kernel(const int* __restrict__ ei, const float* __restrict__ ew,
                             int* __restrict__ bcur, int2* __restrict__ tmp,
                             const float* __restrict__ x, const short* __restrict__ Wt1,
                             short* __restrict__ S1bf) {
  __shared__ __align__(16) short As[128 * LDSTR];
  __shared__ __align__(16) short Bs[128 * 64];
  __shared__ int sc_cnt[NBUCK];
  __shared__ int sc_pos[NBUCK];
  if (blockIdx.x < NSCAT) {
    bscatter_body(blockIdx.x, sc_cnt, sc_pos, ei, ew, bcur, tmp);
  } else {
    int g = blockIdx.x - NSCAT;
    gemm_body<true, 0>(g >> 1, g & 1, As, Bs, x, 512, Wt1, S1bf, nullptr, nullptr, 256, 256);
  }
}

// ---------------- fuseB: bsort (first) || gemm1 m-tiles [MH1, 782) ----------------
__launch_bounds__(256, 2)
__global__ void fuseB_kernel(const int* __restrict__ bbase, const int2* __restrict__ tmp,
                             int2* __restrict__ edat, int* __restrict__ rowptr,
                             const float* __restrict__ x, const short* __restrict__ Wt1,
                             short* __restrict__ S1bf) {
  __shared__ __align__(16) short As[128 * LDSTR];
  __shared__ __align__(16) short Bs[128 * 64];
  __shared__ int so_hist[128];
  __shared__ int so_cur[128];
  if (blockIdx.x < NBUCK) {
    bsort_body(blockIdx.x, so_hist, so_cur, bbase, tmp, edat, rowptr);
  } else {
    int g = blockIdx.x - NBUCK;
    gemm_body<true, 0>(MH1 + (g >> 1), g & 1, As, Bs, x, 512, Wt1, S1bf, nullptr, nullptr, 256, 256);
  }
}

// ---------------- SpMM gather batches: edges broadcast via readlane (SGPR base) ----------------
// NE = 16 (deep pipeline) or 8 (tail). Edge slots >= wcnt carry (src=0, w=0):
// they gather row 0 (L1-resident) and contribute 0 — no branches in the hot path.

template <int NE>
static __device__ __forceinline__ void gat1(int2 me, int b, const short* Sc,
                                            f32x4& acc0, f32x4& acc1) {
  int src[NE]; float wt[NE]; bf16x4 v[NE];
#pragma unroll
  for (int j = 0; j < NE; j++) {
    src[j] = __builtin_amdgcn_readlane(me.x, b + j);
    wt[j] = __builtin_bit_cast(float, __builtin_amdgcn_readlane(me.y, b + j));
  }
#pragma unroll
  for (int j = 0; j < NE; j++) v[j] = *(const bf16x4*)(Sc + (size_t)src[j] * 256);
#pragma unroll
  for (int j = 0; j < NE; j++) {
    if (j & 1) fma4(acc1, wt[j], v[j]); else fma4(acc0, wt[j], v[j]);
  }
}

template <int NE>
static __device__ __forceinline__ void gat2(int2 me, int b, const short* Sc,
                                            f32x2& acc0, f32x2& acc1) {
  int src[NE]; float wt[NE]; bf16x2 v[NE];
#pragma unroll
  for (int j = 0; j < NE; j++) {
    src[j] = __builtin_amdgcn_readlane(me.x, b + j);
    wt[j] = __builtin_bit_cast(float, __builtin_amdgcn_readlane(me.y, b + j));
  }
#pragma unroll
  for (int j = 0; j < NE; j++) v[j] = *(const bf16x2*)(Sc + (size_t)src[j] * 128);
#pragma unroll
  for (int j = 0; j < NE; j++) {
    if (j & 1) fma2(acc1, wt[j], v[j]); else fma2(acc0, wt[j], v[j]);
  }
}

template <int NE>
static __device__ __forceinline__ void gat3(int2 me, int b, const float* S3l,
                                            float& acc0, float& acc1) {
  int src[NE]; float wt[NE]; float v[NE];
#pragma unroll
  for (int j = 0; j < NE; j++) {
    src[j] = __builtin_amdgcn_readlane(me.x, b + j);
    wt[j] = __builtin_bit_cast(float, __builtin_amdgcn_readlane(me.y, b + j));
  }
#pragma unroll
  for (int j = 0; j < NE; j++) v[j] = S3l[(size_t)src[j] * 40];
#pragma unroll
  for (int j = 0; j < NE; j++) {
    if (j & 1) acc1 = fmaf(wt[j], v[j], acc1); else acc0 = fmaf(wt[j], v[j], acc0);
  }
}

// ---------------- SpMM d=256 bf16: persistent waves, 16 gathers in flight ----------------
// Output Hbf chunk-swizzled (per gemm gload_lds contract): the 16B chunk index within
// each 64-element K-tile is XORed with (node&7). node is wave-uniform -> coalesced store.
__launch_bounds__(256, 6)
__global__ void spmm1_kernel(const int* __restrict__ rowptr, const int2* __restrict__ edat,
                             const short* __restrict__ S,
                             const float* __restrict__ bias, short* __restrict__ H) {
  int nw = gridDim.x * 4;
  int wid = blockIdx.x * 4 + (threadIdx.x >> 6);
  int lane = threadIdx.x & 63;
  int c0 = lane * 4;
  const short* Sc = S + c0;
  f32x4 bv = *(const f32x4*)(bias + c0);
  for (int node = wid; node < NNODES; node += nw) {
    f32x4 acc0 = (f32x4){0.f, 0.f, 0.f, 0.f};
    f32x4 acc1 = (f32x4){0.f, 0.f, 0.f, 0.f};
    int beg = rowptr[node], end = rowptr[node + 1];
    for (int w0 = beg; w0 < end; w0 += 64) {
      int wcnt = end - w0;
      if (wcnt > 64) wcnt = 64;
      int2 me = (lane < wcnt) ? edat[w0 + lane] : make_int2(0, 0);
      int g16 = wcnt >> 4, rem = wcnt & 15;
      int b = 0;
      for (int g = 0; g < g16; ++g, b += 16) gat1<16>(me, b, Sc, acc0, acc1);
      if (rem) {
        if (rem > 8) gat1<16>(me, b, Sc, acc0, acc1);
        else gat1<8>(me, b, Sc, acc0, acc1);
      }
    }
    bf16x4 h;
#pragma unroll
    for (int j = 0; j < 4; j++) h[j] = f2bf(fmaxf(acc0[j] + acc1[j] + bv[j], 0.f));
    int c0w = ((lane >> 4) << 6) + ((((lane >> 1) & 7) ^ (node & 7)) << 3) + ((lane & 1) << 2);
    *(bf16x4*)(H + (size_t)node * 256 + c0w) = h;
  }
}

// ---------------- SpMM d=128 bf16: persistent waves, 16 gathers in flight ----------------
// Output Tbf chunk-swizzled like Hbf (consumed by gemm3's gload_lds A-staging).
__launch_bounds__(256, 6)
__global__ void spmm2_kernel(const int* __restrict__ rowptr, const int2* __restrict__ edat,
                             const short* __restrict__ S,
                             const float* __restrict__ bias, short* __restrict__ H) {
  int nw = gridDim.x * 4;
  int wid = blockIdx.x * 4 + (threadIdx.x >> 6);
  int lane = threadIdx.x & 63;
  int c0 = lane * 2;
  const short* Sc = S + c0;
  float b0 = bias[c0], b1 = bias[c0 + 1];
  for (int node = wid; node < NNODES; node += nw) {
    f32x2 acc0 = (f32x2){0.f, 0.f};
    f32x2 acc1 = (f32x2){0.f, 0.f};
    int beg = rowptr[node], end = rowptr[node + 1];
    for (int w0 = beg; w0 < end; w0 += 64) {
      int wcnt = end - w0;
      if (wcnt > 64) wcnt = 64;
      int2 me = (lane < wcnt) ? edat[w0 + lane] : make_int2(0, 0);
      int g16 = wcnt >> 4, rem = wcnt & 15;
      int b = 0;
      for (int g = 0; g < g16; ++g, b += 16) gat2<16>(me, b, Sc, acc0, acc1);
      if (rem) {
        if (rem > 8) gat2<16>(me, b, Sc, acc0, acc1);
        else gat2<8>(me, b, Sc, acc0, acc1);
      }
    }
    bf16x2 h;
    h[0] = f2bf(fmaxf(acc0[0] + acc1[0] + b0, 0.f));
    h[1] = f2bf(fmaxf(acc0[1] + acc1[1] + b1, 0.f));
    int c0w = ((lane >> 5) << 6) + ((((lane >> 2) & 7) ^ (node & 7)) << 3) + ((lane & 3) << 1);
    *(bf16x2*)(H + (size_t)node * 128 + c0w) = h;
  }
}

// ---------------- SpMM d=40 f32 + bias + log_softmax: persistent waves, 16 in flight ----------------
// Lanes 40..63 gather garbage (S3 padded by 64 floats; src*40+lane stays in-bounds) and are
// excluded from the softmax reduce via -inf / 0 masking.
__launch_bounds__(256, 6)
__global__ void spmm3_kernel(const int* __restrict__ rowptr, const int2* __restrict__ edat,
                             const float* __restrict__ S3,
                             const float* __restrict__ b3, float* __restrict__ out1) {
  int nw = gridDim.x * 4;
  int wid = blockIdx.x * 4 + (threadIdx.x >> 6);
  int lane = threadIdx.x & 63;
  bool act = lane < 40;
  const float* S3l = S3 + lane;
  float bl = act ? b3[lane] : 0.f;
  for (int node = wid; node < NNODES; node += nw) {
    float acc0 = 0.f, acc1 = 0.f;
    int beg = rowptr[node], end = rowptr[node + 1];
    for (int w0 = beg; w0 < end; w0 += 64) {
      int wcnt = end - w0;
      if (wcnt > 64) wcnt = 64;
      int2 me = (lane < wcnt) ? edat[w0 + lane] : make_int2(0, 0);
      int g16 = wcnt >> 4, rem = wcnt & 15;
      int b = 0;
      for (int g = 0; g < g16; ++g, b += 16) gat3<16>(me, b, S3l, acc0, acc1);
      if (rem) {
        if (rem > 8) gat3<16>(me, b, S3l, acc0, acc1);
        else gat3<8>(me, b, S3l, acc0, acc1);
      }
    }
    float acc = acc0 + acc1 + bl;
    float v = act ? acc : -__builtin_inff();
    for (int off = 32; off > 0; off >>= 1) v = fmaxf(v, __shfl_xor(v, off));
    float e = act ? expf(acc - v) : 0.f;
    for (int off = 32; off > 0; off >>= 1) e += __shfl_xor(e, off);
    float ls = logf(e);
    if (act) out1[(size_t)node * 40 + lane] = acc - v - ls;
  }
}

extern "C" void kernel_launch(void* const* d_in, const int* in_sizes, int n_in,
                              void* d_out, int out_size, void* d_ws, size_t ws_size,
                              hipStream_t stream) {
  const float* x  = (const float*)d_in[0];
  const int*   ei = (const int*)d_in[1];
  const float* ew = (const float*)d_in[2];
  const float* W1 = (const float*)d_in[3];
  const float* b1 = (const float*)d_in[4];
  const float* W2 = (const float*)d_in[5];
  const float* b2 = (const float*)d_in[6];
  const float* W3 = (const float*)d_in[7];
  const float* b3 = (const float*)d_in[8];
  const float* We = (const float*)d_in[9];
  const float* be = (const float*)d_in[10];
  float* out1 = (float*)d_out;
  float* out2 = (float*)d_out + (size_t)NNODES * 40;

  char* w = (char*)d_ws;
  size_t off = 0;
  auto alloc = [&](size_t bytes) -> char* {
    char* p = w + off;
    off += (bytes + 255) & ~(size_t)255;
    return p;
  };
  int*   rowptr = (int*)alloc((size_t)(NNODES + 1) * 4);
  int*   bcnt   = (int*)alloc((size_t)NBUCK * 4);
  int*   bbase  = (int*)alloc((size_t)(NBUCK + 1) * 4);
  int*   bcur   = (int*)alloc((size_t)NBUCK * 4);
  int2*  edat   = (int2*)alloc((size_t)NEDGES * 8);
  short* Wt1    = (short*)alloc((size_t)256 * 512 * 2);
  short* Wt2e   = (short*)alloc((size_t)256 * 256 * 2);
  short* Wt3    = (short*)alloc((size_t)128 * 128 * 2);
  short* S1bf   = (short*)alloc((size_t)NNODES * 256 * 2);
  short* Hbf    = (short*)alloc((size_t)NNODES * 256 * 2);
  short* S2bf   = (short*)alloc((size_t)NNODES * 128 * 2);
  short* Tbf    = (short*)alloc((size_t)NNODES * 128 * 2);
  float* S3     = (float*)alloc(((size_t)NNODES * 40 + 64) * 4);  // +64 floats: lane 40..63 overread pad
  int2*  tmp    = (int2*)S3;  // alias: tmp (12.8 MB) dead before gemm3 writes S3

  // --- front: weight transposes + bucket histogram (independent, fused) ---
  hipMemsetAsync(bcnt, 0, (size_t)NBUCK * 4, stream);
  front_kernel<<<FRONT_BLOCKS, 256, 0, stream>>>(W1, Wt1, W2, We, Wt2e, W3, Wt3, ei, bcnt);
  bscan_kernel<<<1, 1024, 0, stream>>>(bcnt, bbase, bcur, rowptr);

  // --- fuseA: bucket scatter || gemm1 first half;  fuseB: bucket sort || gemm1 second half ---
  fuseA_kernel<<<NSCAT + MH1 * 2, 256, 0, stream>>>(ei, ew, bcur, tmp, x, Wt1, S1bf);
  fuseB_kernel<<<NBUCK + (782 - MH1) * 2, 256, 0, stream>>>(bbase, tmp, edat, rowptr, x, Wt1, S1bf);

  int gblocks = (NNODES + 127) / 128;

  spmm1_kernel<<<SPBLK, 256, 0, stream>>>(rowptr, edat, S1bf, b1, Hbf);
  gemm_tiled<false, 2><<<dim3(2, gblocks), 256, 0, stream>>>(Hbf, 256, Wt2e, S2bf, out2, be, 256, 128);
  spmm2_kernel<<<SPBLK, 256, 0, stream>>>(rowptr, edat, S2bf, b2, Tbf);
  gemm_tiled<false, 1><<<dim3(1, gblocks), 256, 0, stream>>>(Tbf, 128, Wt3, nullptr, S3, nullptr, 40, 40);
  spmm3_kernel<<<SPBLK, 256, 0, stream>>>(rowptr, edat, S3, b3, out1);
}